// Round 15
// baseline (209.054 us; speedup 1.0000x reference)
//
#include <hip/hip_runtime.h>

// SGConv: K=3 hops of \hat{A} x (symmetric gcn_norm w/ self-loops), then Linear.
// N=100000, E=1600000, F_in=32, F_out=64.
// Round 15 (from R14 @ 202.8us): hop model = L1-MSHR/latency wall (~15 cy/line/CU,
// not L2 BW). Levers: deeper MLP (unroll 8) + protect L2 state residency
// (nontemporal gout stores + col loads so 6.4MB gin stays hot; misses currently
// split L2/L3). Build path unchanged from R14.

#define F_IN 32
#define F_OUT 64
#define SB_SHIFT 13                  // 8192 nodes per super-bucket
#define NSB_MAX 16
#define SUB_SHIFT 8                  // 256 nodes per sub-bucket
#define SUB (1 << SUB_SHIFT)
#define SPS 32                       // subs per super (8192/256)
#define EPB1 2048
#define EPB2 4096
#define SCAP 147456                  // super slab cap (mean 131072, sd ~347)
#define SUBCAP 6144                  // sub slab cap (mean 4096, sd ~64)
#define BPS (SCAP / EPB2)            // 36 blocks per super in k_bin2

typedef float f4 __attribute__((ext_vector_type(4)));
typedef _Float16 h4 __attribute__((ext_vector_type(4)));   // 8B
typedef int i2 __attribute__((ext_vector_type(2)));

// ---------- Level-1 bin: 13 supers; per-wave replicated hist/cursors ----------
__global__ __launch_bounds__(256) void k_bin1(const int* __restrict__ ei,
                                              int* __restrict__ scur,
                                              unsigned* __restrict__ b1, int E) {
    __shared__ unsigned stage[EPB1];          // 8 KB
    __shared__ unsigned char bidl[EPB1];      // 2 KB
    __shared__ int h4w[4][NSB_MAX];           // per-wave hist
    __shared__ int f4w[4][NSB_MAX];           // per-wave cursors
    __shared__ int lscanx[NSB_MAX], lbase[NSB_MAX];
    unsigned rec[EPB1 / 256];
    int      bk[EPB1 / 256];
    int tid = threadIdx.x;
    int wv = tid >> 6;
    int base = blockIdx.x * EPB1;
    int cnt = E - base; if (cnt > EPB1) cnt = EPB1;

    if (tid < 64) { h4w[tid >> 4][tid & 15] = 0; }
    __syncthreads();
#pragma unroll
    for (int k = 0; k < EPB1 / 256; ++k) {
        int i = base + k * 256 + tid;
        bk[k] = -1;
        if (i < E) {
            unsigned s = (unsigned)ei[i];
            unsigned d = (unsigned)ei[E + i];
            int b = d >> SB_SHIFT;
            rec[k] = (s << SB_SHIFT) | (d & ((1u << SB_SHIFT) - 1));
            bk[k] = b;
            atomicAdd(&h4w[wv][b], 1);
        }
    }
    __syncthreads();
    if (tid < 16) {
        int t0 = h4w[0][tid], t1 = h4w[1][tid], t2 = h4w[2][tid], t3 = h4w[3][tid];
        int tot = t0 + t1 + t2 + t3;
        int inc = tot;
#pragma unroll
        for (int off = 1; off < 16; off <<= 1) {
            int t = __shfl_up(inc, off);
            if (tid >= off) inc += t;
        }
        int excl = inc - tot;
        lscanx[tid] = excl;
        lbase[tid] = tot ? atomicAdd(&scur[tid], tot) : 0;
        f4w[0][tid] = excl;
        f4w[1][tid] = excl + t0;
        f4w[2][tid] = excl + t0 + t1;
        f4w[3][tid] = excl + t0 + t1 + t2;
    }
    __syncthreads();
#pragma unroll
    for (int k = 0; k < EPB1 / 256; ++k) {
        if (bk[k] >= 0) {
            int loc = atomicAdd(&f4w[wv][bk[k]], 1);
            stage[loc] = rec[k];
            bidl[loc] = (unsigned char)bk[k];
        }
    }
    __syncthreads();
    for (int k = 0; k < EPB1 / 256; ++k) {
        int idx = k * 256 + tid;
        if (idx < cnt) {
            int b = bidl[idx];
            b1[(size_t)b * SCAP + lbase[b] + (idx - lscanx[b])] = stage[idx];
        }
    }
}

// ---------- Level-2 bin: 32 subs per super; per-wave replicated ----------
__global__ __launch_bounds__(256) void k_bin2(const unsigned* __restrict__ b1,
                                              const int* __restrict__ scur,
                                              int* __restrict__ subcur,
                                              unsigned* __restrict__ b2) {
    int sb = blockIdx.x / BPS;
    int base = (blockIdx.x % BPS) * EPB2;
    int count = scur[sb];
    if (base >= count) return;
    int cnt = count - base; if (cnt > EPB2) cnt = EPB2;
    const unsigned* src = b1 + (size_t)sb * SCAP + base;

    __shared__ unsigned stage[EPB2];          // 16 KB
    __shared__ unsigned char bidl[EPB2];      // 4 KB
    __shared__ int h4w[4][SPS];
    __shared__ int f4w[4][SPS];
    __shared__ int lscanx[SPS], lbase[SPS];
    unsigned rec[EPB2 / 256];
    int tid = threadIdx.x;
    int wv = tid >> 6;
    if (tid < 128) h4w[tid >> 5][tid & 31] = 0;
    __syncthreads();
#pragma unroll
    for (int k = 0; k < EPB2 / 256; ++k) {
        int i = k * 256 + tid;
        rec[k] = 0xFFFFFFFFu;
        if (i < cnt) {
            unsigned r = src[i];
            rec[k] = r;
            atomicAdd(&h4w[wv][(r >> SUB_SHIFT) & (SPS - 1)], 1);
        }
    }
    __syncthreads();
    if (tid < 32) {
        int t0 = h4w[0][tid], t1 = h4w[1][tid], t2 = h4w[2][tid], t3 = h4w[3][tid];
        int tot = t0 + t1 + t2 + t3;
        int inc = tot;
#pragma unroll
        for (int off = 1; off < 32; off <<= 1) {
            int t = __shfl_up(inc, off);
            if (tid >= off) inc += t;
        }
        int excl = inc - tot;
        lscanx[tid] = excl;
        lbase[tid] = tot ? atomicAdd(&subcur[sb * SPS + tid], tot) : 0;
        f4w[0][tid] = excl;
        f4w[1][tid] = excl + t0;
        f4w[2][tid] = excl + t0 + t1;
        f4w[3][tid] = excl + t0 + t1 + t2;
    }
    __syncthreads();
#pragma unroll
    for (int k = 0; k < EPB2 / 256; ++k) {
        if (rec[k] != 0xFFFFFFFFu) {
            int b = (rec[k] >> SUB_SHIFT) & (SPS - 1);
            int loc = atomicAdd(&f4w[wv][b], 1);
            stage[loc] = rec[k];
            bidl[loc] = (unsigned char)b;
        }
    }
    __syncthreads();
    for (int k = 0; k < EPB2 / 256; ++k) {
        int idx = k * 256 + tid;
        if (idx < cnt) {
            unsigned r = stage[idx];
            int b = bidl[idx];
            unsigned packed = ((r >> SB_SHIFT) << SUB_SHIFT) | (r & (SUB - 1));
            b2[(size_t)(sb * SPS + b) * SUBCAP + lbase[b] + (idx - lscanx[b])] = packed;
        }
    }
}

// ---------- fill3: one 256-thr block per 256-node sub + fused prescale ----------
__global__ __launch_bounds__(256) void k_fill3(const unsigned* __restrict__ b2,
                                               const int* __restrict__ subcur,
                                               const f4* __restrict__ x,
                                               float* __restrict__ dinv,
                                               i2* __restrict__ rp2,
                                               int* __restrict__ col,
                                               h4* __restrict__ g0, int N) {
    __shared__ unsigned stage[SUBCAP];        // 24 KB
    __shared__ int h[SUB];
    __shared__ float dl[SUB];
    __shared__ int wsum[4];
    int tid = threadIdx.x;
    int g = blockIdx.x;
    int count = subcur[g];
    int sbase = g * SUBCAP;
    int n0 = g << SUB_SHIFT;

    h[tid] = 0;
    for (int e = tid; e < count; e += 256) stage[e] = b2[(size_t)sbase + e];
    __syncthreads();
    for (int e = tid; e < count; e += 256) atomicAdd(&h[stage[e] & (SUB - 1)], 1);
    __syncthreads();

    int deg = h[tid];
    int lane = tid & 63, wid = tid >> 6;
    int inc = deg;
#pragma unroll
    for (int off = 1; off < 64; off <<= 1) {
        int t = __shfl_up(inc, off);
        if (lane >= off) inc += t;
    }
    if (lane == 63) wsum[wid] = inc;
    __syncthreads();
    if (wid == 0) {
        int v = (lane < 4) ? wsum[lane] : 0;
#pragma unroll
        for (int off = 1; off < 4; off <<= 1) {
            int t = __shfl_up(v, off);
            if (lane >= off) v += t;
        }
        if (lane < 4) wsum[lane] = v;
    }
    __syncthreads();
    int incl = inc + (wid ? wsum[wid - 1] : 0);
    int excl = incl - deg;

    int node = n0 + tid;
    float di = rsqrtf(1.0f + (float)deg);
    dl[tid] = di;
    if (node < N) {
        dinv[node] = di;
        rp2[node] = (i2){sbase + excl, sbase + incl};
    }
    h[tid] = excl;
    __syncthreads();

    for (int e = tid; e < count; e += 256) {
        unsigned r = stage[e];
        int slot = sbase + atomicAdd(&h[r & (SUB - 1)], 1);
        col[slot] = (int)(r >> SUB_SHIFT);
    }

    for (int idx = tid; idx < SUB * 8; idx += 256) {
        int nl = idx >> 3;
        int gi = n0 * 8 + idx;
        if (n0 + nl < N) {
            f4 v = dl[nl] * x[gi];
            g0[gi] = __builtin_convertvector(v, h4);
        }
    }
}

// ---------- Mid hop (hops 1,2): 8 lanes/row, unroll-8, nt col + nt store ----------
__global__ __launch_bounds__(256) void k_hop_gather(const i2* __restrict__ rp2,
                                                    const int* __restrict__ col,
                                                    const float* __restrict__ dinv,
                                                    const h4* __restrict__ gin,
                                                    h4* __restrict__ gout, int N) {
    int t = blockIdx.x * blockDim.x + threadIdx.x;
    int n = t >> 3;
    if (n >= N) return;
    int q = t & 7;
    i2 r2 = rp2[n];
    int e0 = r2.x, e1 = r2.y;
    f4 a0 = __builtin_convertvector(gin[n * 8 + q], f4);  // self-loop term
    f4 a1 = {0.f, 0.f, 0.f, 0.f};
    int e = e0;
    for (; e + 7 < e1; e += 8) {
        int s0 = __builtin_nontemporal_load(col + e);
        int s1 = __builtin_nontemporal_load(col + e + 1);
        int s2 = __builtin_nontemporal_load(col + e + 2);
        int s3 = __builtin_nontemporal_load(col + e + 3);
        int s4 = __builtin_nontemporal_load(col + e + 4);
        int s5 = __builtin_nontemporal_load(col + e + 5);
        int s6 = __builtin_nontemporal_load(col + e + 6);
        int s7 = __builtin_nontemporal_load(col + e + 7);
        h4 h0 = gin[s0 * 8 + q];
        h4 h1 = gin[s1 * 8 + q];
        h4 h2 = gin[s2 * 8 + q];
        h4 h3 = gin[s3 * 8 + q];
        h4 h5_0 = gin[s4 * 8 + q];
        h4 h5_1 = gin[s5 * 8 + q];
        h4 h5_2 = gin[s6 * 8 + q];
        h4 h5_3 = gin[s7 * 8 + q];
        a0 += __builtin_convertvector(h0, f4);
        a1 += __builtin_convertvector(h1, f4);
        a0 += __builtin_convertvector(h2, f4);
        a1 += __builtin_convertvector(h3, f4);
        a0 += __builtin_convertvector(h5_0, f4);
        a1 += __builtin_convertvector(h5_1, f4);
        a0 += __builtin_convertvector(h5_2, f4);
        a1 += __builtin_convertvector(h5_3, f4);
    }
    for (; e + 3 < e1; e += 4) {
        int s0 = __builtin_nontemporal_load(col + e);
        int s1 = __builtin_nontemporal_load(col + e + 1);
        int s2 = __builtin_nontemporal_load(col + e + 2);
        int s3 = __builtin_nontemporal_load(col + e + 3);
        h4 h0 = gin[s0 * 8 + q];
        h4 h1 = gin[s1 * 8 + q];
        h4 h2 = gin[s2 * 8 + q];
        h4 h3 = gin[s3 * 8 + q];
        a0 += __builtin_convertvector(h0, f4);
        a1 += __builtin_convertvector(h1, f4);
        a0 += __builtin_convertvector(h2, f4);
        a1 += __builtin_convertvector(h3, f4);
    }
    for (; e < e1; ++e)
        a0 += __builtin_convertvector(gin[__builtin_nontemporal_load(col + e) * 8 + q], f4);
    float di = dinv[n];
    float sc = di * di;
    f4 r = sc * (a0 + a1);
    __builtin_nontemporal_store(__builtin_convertvector(r, h4), &gout[n * 8 + q]);
}

// ---------- Final hop FUSED with linear; conflict-free epilogue ----------
__global__ __launch_bounds__(256) void k_hop3_linear(const i2* __restrict__ rp2,
                                                     const int* __restrict__ col,
                                                     const float* __restrict__ dinv,
                                                     const h4* __restrict__ gin,
                                                     const float* __restrict__ W,
                                                     const float* __restrict__ bias,
                                                     float* __restrict__ out, int N) {
    __shared__ float Wl[F_OUT][F_IN + 1];   // 8.4 KB
    __shared__ float hl[32][F_IN + 1];      // 4.2 KB
    int tid = threadIdx.x;
    for (int idx = tid; idx < F_OUT * F_IN; idx += 256)
        Wl[idx >> 5][idx & 31] = W[idx];

    int nl = tid >> 3;
    int q = tid & 7;
    int nbase = blockIdx.x * 32;
    int n = nbase + nl;
    if (n < N) {
        i2 r2 = rp2[n];
        int e0 = r2.x, e1 = r2.y;
        f4 a0 = __builtin_convertvector(gin[n * 8 + q], f4);
        f4 a1 = {0.f, 0.f, 0.f, 0.f};
        int e = e0;
        for (; e + 7 < e1; e += 8) {
            int s0 = __builtin_nontemporal_load(col + e);
            int s1 = __builtin_nontemporal_load(col + e + 1);
            int s2 = __builtin_nontemporal_load(col + e + 2);
            int s3 = __builtin_nontemporal_load(col + e + 3);
            int s4 = __builtin_nontemporal_load(col + e + 4);
            int s5 = __builtin_nontemporal_load(col + e + 5);
            int s6 = __builtin_nontemporal_load(col + e + 6);
            int s7 = __builtin_nontemporal_load(col + e + 7);
            h4 h0 = gin[s0 * 8 + q];
            h4 h1 = gin[s1 * 8 + q];
            h4 h2 = gin[s2 * 8 + q];
            h4 h3 = gin[s3 * 8 + q];
            h4 h5_0 = gin[s4 * 8 + q];
            h4 h5_1 = gin[s5 * 8 + q];
            h4 h5_2 = gin[s6 * 8 + q];
            h4 h5_3 = gin[s7 * 8 + q];
            a0 += __builtin_convertvector(h0, f4);
            a1 += __builtin_convertvector(h1, f4);
            a0 += __builtin_convertvector(h2, f4);
            a1 += __builtin_convertvector(h3, f4);
            a0 += __builtin_convertvector(h5_0, f4);
            a1 += __builtin_convertvector(h5_1, f4);
            a0 += __builtin_convertvector(h5_2, f4);
            a1 += __builtin_convertvector(h5_3, f4);
        }
        for (; e + 3 < e1; e += 4) {
            int s0 = __builtin_nontemporal_load(col + e);
            int s1 = __builtin_nontemporal_load(col + e + 1);
            int s2 = __builtin_nontemporal_load(col + e + 2);
            int s3 = __builtin_nontemporal_load(col + e + 3);
            h4 h0 = gin[s0 * 8 + q];
            h4 h1 = gin[s1 * 8 + q];
            h4 h2 = gin[s2 * 8 + q];
            h4 h3 = gin[s3 * 8 + q];
            a0 += __builtin_convertvector(h0, f4);
            a1 += __builtin_convertvector(h1, f4);
            a0 += __builtin_convertvector(h2, f4);
            a1 += __builtin_convertvector(h3, f4);
        }
        for (; e < e1; ++e)
            a0 += __builtin_convertvector(gin[__builtin_nontemporal_load(col + e) * 8 + q], f4);
        float di = dinv[n];
        f4 r = di * (a0 + a1);
        hl[nl][q * 4 + 0] = r.x;
        hl[nl][q * 4 + 1] = r.y;
        hl[nl][q * 4 + 2] = r.z;
        hl[nl][q * 4 + 3] = r.w;
    }
    __syncthreads();
    int o = tid & 63;
    float wreg[F_IN];
#pragma unroll
    for (int f = 0; f < F_IN; ++f) wreg[f] = Wl[o][f];
    float bv = bias[o];
    int nchunk = tid >> 6;
#pragma unroll
    for (int p = 0; p < 8; ++p) {
        int nloc = p * 4 + nchunk;
        int nn = nbase + nloc;
        if (nn < N) {
            float acc = bv;
#pragma unroll
            for (int f = 0; f < F_IN; ++f) acc += hl[nloc][f] * wreg[f];
            out[(size_t)nn * F_OUT + o] = acc;
        }
    }
}

extern "C" void kernel_launch(void* const* d_in, const int* in_sizes, int n_in,
                              void* d_out, int out_size, void* d_ws, size_t ws_size,
                              hipStream_t stream) {
    const float* x  = (const float*)d_in[0];
    const int*   ei = (const int*)d_in[1];   // [2,E] int32: src row then dst row
    const float* W  = (const float*)d_in[2];
    const float* b  = (const float*)d_in[3];
    float* out = (float*)d_out;

    const int N = in_sizes[0] / F_IN;
    const int E = in_sizes[1] / 2;
    const int NSB  = (N + (1 << SB_SHIFT) - 1) >> SB_SHIFT;   // 13
    const int NSUB = (N + SUB - 1) >> SUB_SHIFT;              // 391

    int* scur   = (int*)d_ws;
    int* subcur = scur + NSB_MAX;
    i2*  rp2    = (i2*)(subcur + NSB_MAX * SPS);
    float* dinv = (float*)(rp2 + N);
    unsigned* b1 = (unsigned*)(((uintptr_t)(dinv + N) + 255) & ~(uintptr_t)255);
    unsigned* b2 = b1 + (size_t)NSB_MAX * SCAP;
    int* col     = (int*)(b2 + (size_t)NSB_MAX * SPS * SUBCAP);
    _Float16* hA = (_Float16*)(((uintptr_t)(col + (size_t)NSB_MAX * SPS * SUBCAP) + 255)
                               & ~(uintptr_t)255);
    _Float16* hB  = hA + (size_t)N * F_IN;
    _Float16* hB2 = hB + (size_t)N * F_IN;

    const int B = 256;
    dim3 blk(B);

    hipMemsetAsync(scur, 0, (NSB_MAX + NSB_MAX * SPS) * sizeof(int), stream);

    k_bin1<<<dim3((E + EPB1 - 1) / EPB1), blk, 0, stream>>>(ei, scur, b1, E);
    k_bin2<<<dim3(NSB * BPS), blk, 0, stream>>>(b1, scur, subcur, b2);

    k_fill3<<<dim3(NSUB), blk, 0, stream>>>(b2, subcur, (const f4*)x,
                                            dinv, rp2, col, (h4*)hA, N);

    dim3 gHop(((size_t)N * 8 + B - 1) / B);
    k_hop_gather<<<gHop, blk, 0, stream>>>(rp2, col, dinv, (const h4*)hA, (h4*)hB, N);
    k_hop_gather<<<gHop, blk, 0, stream>>>(rp2, col, dinv, (const h4*)hB, (h4*)hB2, N);

    k_hop3_linear<<<dim3((N + 31) / 32), blk, 0, stream>>>(rp2, col, dinv,
                                                           (const h4*)hB2, W, b, out, N);
}

// Round 16
// 200.794 us; speedup vs baseline: 1.0411x; 1.0411x over previous
//
#include <hip/hip_runtime.h>

// SGConv: K=3 hops of \hat{A} x (symmetric gcn_norm w/ self-loops), then Linear.
// N=100000, E=1600000, F_in=32, F_out=64.
// Round 16: revert to the R14 configuration (measured best, 202.8us).
// R15's unroll-8 + nontemporal hints regressed (+6us): hop is MSHR/latency
// bound; deeper static unroll adds VGPR/tail cost without raising the
// random-line-touch service rate, and nt hints don't change the ~40/60
// L2/L3 fill split (state 6.4MB > 4MB/XCD L2). Keep: two-level radix build,
// per-wave replicated bin counters, fill3+prescale fusion, unroll-4 hops,
// conflict-free fused hop3+linear epilogue.

#define F_IN 32
#define F_OUT 64
#define SB_SHIFT 13                  // 8192 nodes per super-bucket
#define NSB_MAX 16
#define SUB_SHIFT 8                  // 256 nodes per sub-bucket
#define SUB (1 << SUB_SHIFT)
#define SPS 32                       // subs per super (8192/256)
#define EPB1 2048
#define EPB2 4096
#define SCAP 147456                  // super slab cap (mean 131072, sd ~347)
#define SUBCAP 6144                  // sub slab cap (mean 4096, sd ~64)
#define BPS (SCAP / EPB2)            // 36 blocks per super in k_bin2

typedef float f4 __attribute__((ext_vector_type(4)));
typedef _Float16 h4 __attribute__((ext_vector_type(4)));   // 8B
typedef int i2 __attribute__((ext_vector_type(2)));

// ---------- Level-1 bin: 13 supers; per-wave replicated hist/cursors ----------
__global__ __launch_bounds__(256) void k_bin1(const int* __restrict__ ei,
                                              int* __restrict__ scur,
                                              unsigned* __restrict__ b1, int E) {
    __shared__ unsigned stage[EPB1];          // 8 KB
    __shared__ unsigned char bidl[EPB1];      // 2 KB
    __shared__ int h4w[4][NSB_MAX];           // per-wave hist
    __shared__ int f4w[4][NSB_MAX];           // per-wave cursors
    __shared__ int lscanx[NSB_MAX], lbase[NSB_MAX];
    unsigned rec[EPB1 / 256];
    int      bk[EPB1 / 256];
    int tid = threadIdx.x;
    int wv = tid >> 6;
    int base = blockIdx.x * EPB1;
    int cnt = E - base; if (cnt > EPB1) cnt = EPB1;

    if (tid < 64) { h4w[tid >> 4][tid & 15] = 0; }
    __syncthreads();
#pragma unroll
    for (int k = 0; k < EPB1 / 256; ++k) {
        int i = base + k * 256 + tid;
        bk[k] = -1;
        if (i < E) {
            unsigned s = (unsigned)ei[i];
            unsigned d = (unsigned)ei[E + i];
            int b = d >> SB_SHIFT;
            rec[k] = (s << SB_SHIFT) | (d & ((1u << SB_SHIFT) - 1));
            bk[k] = b;
            atomicAdd(&h4w[wv][b], 1);
        }
    }
    __syncthreads();
    if (tid < 16) {
        int t0 = h4w[0][tid], t1 = h4w[1][tid], t2 = h4w[2][tid], t3 = h4w[3][tid];
        int tot = t0 + t1 + t2 + t3;
        int inc = tot;
#pragma unroll
        for (int off = 1; off < 16; off <<= 1) {
            int t = __shfl_up(inc, off);
            if (tid >= off) inc += t;
        }
        int excl = inc - tot;
        lscanx[tid] = excl;
        lbase[tid] = tot ? atomicAdd(&scur[tid], tot) : 0;
        f4w[0][tid] = excl;
        f4w[1][tid] = excl + t0;
        f4w[2][tid] = excl + t0 + t1;
        f4w[3][tid] = excl + t0 + t1 + t2;
    }
    __syncthreads();
#pragma unroll
    for (int k = 0; k < EPB1 / 256; ++k) {
        if (bk[k] >= 0) {
            int loc = atomicAdd(&f4w[wv][bk[k]], 1);
            stage[loc] = rec[k];
            bidl[loc] = (unsigned char)bk[k];
        }
    }
    __syncthreads();
    for (int k = 0; k < EPB1 / 256; ++k) {
        int idx = k * 256 + tid;
        if (idx < cnt) {
            int b = bidl[idx];
            b1[(size_t)b * SCAP + lbase[b] + (idx - lscanx[b])] = stage[idx];
        }
    }
}

// ---------- Level-2 bin: 32 subs per super; per-wave replicated ----------
__global__ __launch_bounds__(256) void k_bin2(const unsigned* __restrict__ b1,
                                              const int* __restrict__ scur,
                                              int* __restrict__ subcur,
                                              unsigned* __restrict__ b2) {
    int sb = blockIdx.x / BPS;
    int base = (blockIdx.x % BPS) * EPB2;
    int count = scur[sb];
    if (base >= count) return;
    int cnt = count - base; if (cnt > EPB2) cnt = EPB2;
    const unsigned* src = b1 + (size_t)sb * SCAP + base;

    __shared__ unsigned stage[EPB2];          // 16 KB
    __shared__ unsigned char bidl[EPB2];      // 4 KB
    __shared__ int h4w[4][SPS];
    __shared__ int f4w[4][SPS];
    __shared__ int lscanx[SPS], lbase[SPS];
    unsigned rec[EPB2 / 256];
    int tid = threadIdx.x;
    int wv = tid >> 6;
    if (tid < 128) h4w[tid >> 5][tid & 31] = 0;
    __syncthreads();
#pragma unroll
    for (int k = 0; k < EPB2 / 256; ++k) {
        int i = k * 256 + tid;
        rec[k] = 0xFFFFFFFFu;
        if (i < cnt) {
            unsigned r = src[i];
            rec[k] = r;
            atomicAdd(&h4w[wv][(r >> SUB_SHIFT) & (SPS - 1)], 1);
        }
    }
    __syncthreads();
    if (tid < 32) {
        int t0 = h4w[0][tid], t1 = h4w[1][tid], t2 = h4w[2][tid], t3 = h4w[3][tid];
        int tot = t0 + t1 + t2 + t3;
        int inc = tot;
#pragma unroll
        for (int off = 1; off < 32; off <<= 1) {
            int t = __shfl_up(inc, off);
            if (tid >= off) inc += t;
        }
        int excl = inc - tot;
        lscanx[tid] = excl;
        lbase[tid] = tot ? atomicAdd(&subcur[sb * SPS + tid], tot) : 0;
        f4w[0][tid] = excl;
        f4w[1][tid] = excl + t0;
        f4w[2][tid] = excl + t0 + t1;
        f4w[3][tid] = excl + t0 + t1 + t2;
    }
    __syncthreads();
#pragma unroll
    for (int k = 0; k < EPB2 / 256; ++k) {
        if (rec[k] != 0xFFFFFFFFu) {
            int b = (rec[k] >> SUB_SHIFT) & (SPS - 1);
            int loc = atomicAdd(&f4w[wv][b], 1);
            stage[loc] = rec[k];
            bidl[loc] = (unsigned char)b;
        }
    }
    __syncthreads();
    for (int k = 0; k < EPB2 / 256; ++k) {
        int idx = k * 256 + tid;
        if (idx < cnt) {
            unsigned r = stage[idx];
            int b = bidl[idx];
            unsigned packed = ((r >> SB_SHIFT) << SUB_SHIFT) | (r & (SUB - 1));
            b2[(size_t)(sb * SPS + b) * SUBCAP + lbase[b] + (idx - lscanx[b])] = packed;
        }
    }
}

// ---------- fill3: one 256-thr block per 256-node sub + fused prescale ----------
__global__ __launch_bounds__(256) void k_fill3(const unsigned* __restrict__ b2,
                                               const int* __restrict__ subcur,
                                               const f4* __restrict__ x,
                                               float* __restrict__ dinv,
                                               i2* __restrict__ rp2,
                                               int* __restrict__ col,
                                               h4* __restrict__ g0, int N) {
    __shared__ unsigned stage[SUBCAP];        // 24 KB
    __shared__ int h[SUB];
    __shared__ float dl[SUB];
    __shared__ int wsum[4];
    int tid = threadIdx.x;
    int g = blockIdx.x;
    int count = subcur[g];
    int sbase = g * SUBCAP;
    int n0 = g << SUB_SHIFT;

    h[tid] = 0;
    for (int e = tid; e < count; e += 256) stage[e] = b2[(size_t)sbase + e];
    __syncthreads();
    for (int e = tid; e < count; e += 256) atomicAdd(&h[stage[e] & (SUB - 1)], 1);
    __syncthreads();

    int deg = h[tid];
    int lane = tid & 63, wid = tid >> 6;
    int inc = deg;
#pragma unroll
    for (int off = 1; off < 64; off <<= 1) {
        int t = __shfl_up(inc, off);
        if (lane >= off) inc += t;
    }
    if (lane == 63) wsum[wid] = inc;
    __syncthreads();
    if (wid == 0) {
        int v = (lane < 4) ? wsum[lane] : 0;
#pragma unroll
        for (int off = 1; off < 4; off <<= 1) {
            int t = __shfl_up(v, off);
            if (lane >= off) v += t;
        }
        if (lane < 4) wsum[lane] = v;
    }
    __syncthreads();
    int incl = inc + (wid ? wsum[wid - 1] : 0);
    int excl = incl - deg;

    int node = n0 + tid;
    float di = rsqrtf(1.0f + (float)deg);
    dl[tid] = di;
    if (node < N) {
        dinv[node] = di;
        rp2[node] = (i2){sbase + excl, sbase + incl};
    }
    h[tid] = excl;
    __syncthreads();

    for (int e = tid; e < count; e += 256) {
        unsigned r = stage[e];
        int slot = sbase + atomicAdd(&h[r & (SUB - 1)], 1);
        col[slot] = (int)(r >> SUB_SHIFT);
    }

    // fused prescale for this block's nodes: g0 = fp16(dinv .* x), coalesced
    for (int idx = tid; idx < SUB * 8; idx += 256) {
        int nl = idx >> 3;
        int gi = n0 * 8 + idx;
        if (n0 + nl < N) {
            f4 v = dl[nl] * x[gi];
            g0[gi] = __builtin_convertvector(v, h4);
        }
    }
}

// ---------- Mid hop (hops 1,2): 8 lanes/row, unroll-4 (R8/R14 best config) ----------
__global__ __launch_bounds__(256) void k_hop_gather(const i2* __restrict__ rp2,
                                                    const int* __restrict__ col,
                                                    const float* __restrict__ dinv,
                                                    const h4* __restrict__ gin,
                                                    h4* __restrict__ gout, int N) {
    int t = blockIdx.x * blockDim.x + threadIdx.x;
    int n = t >> 3;
    if (n >= N) return;
    int q = t & 7;
    i2 r2 = rp2[n];
    int e0 = r2.x, e1 = r2.y;
    f4 a0 = __builtin_convertvector(gin[n * 8 + q], f4);  // self-loop term
    f4 a1 = {0.f, 0.f, 0.f, 0.f};
    int e = e0;
    for (; e + 3 < e1; e += 4) {
        int s0 = col[e], s1 = col[e + 1], s2 = col[e + 2], s3 = col[e + 3];
        h4 h0 = gin[s0 * 8 + q];
        h4 h1 = gin[s1 * 8 + q];
        h4 h2 = gin[s2 * 8 + q];
        h4 h3 = gin[s3 * 8 + q];
        a0 += __builtin_convertvector(h0, f4);
        a1 += __builtin_convertvector(h1, f4);
        a0 += __builtin_convertvector(h2, f4);
        a1 += __builtin_convertvector(h3, f4);
    }
    for (; e < e1; ++e) a0 += __builtin_convertvector(gin[col[e] * 8 + q], f4);
    float di = dinv[n];
    float sc = di * di;
    f4 r = sc * (a0 + a1);
    gout[n * 8 + q] = __builtin_convertvector(r, h4);
}

// ---------- Final hop FUSED with linear; conflict-free epilogue ----------
// Block = 256 thr = 32 nodes x 8 lanes (gather), then 8 passes of 4 nodes x 64 o.
__global__ __launch_bounds__(256) void k_hop3_linear(const i2* __restrict__ rp2,
                                                     const int* __restrict__ col,
                                                     const float* __restrict__ dinv,
                                                     const h4* __restrict__ gin,
                                                     const float* __restrict__ W,
                                                     const float* __restrict__ bias,
                                                     float* __restrict__ out, int N) {
    __shared__ float Wl[F_OUT][F_IN + 1];   // 8.4 KB
    __shared__ float hl[32][F_IN + 1];      // 4.2 KB
    int tid = threadIdx.x;
    for (int idx = tid; idx < F_OUT * F_IN; idx += 256)
        Wl[idx >> 5][idx & 31] = W[idx];

    int nl = tid >> 3;                 // 0..31 local node
    int q = tid & 7;
    int nbase = blockIdx.x * 32;
    int n = nbase + nl;
    if (n < N) {
        i2 r2 = rp2[n];
        int e0 = r2.x, e1 = r2.y;
        f4 a0 = __builtin_convertvector(gin[n * 8 + q], f4);
        f4 a1 = {0.f, 0.f, 0.f, 0.f};
        int e = e0;
        for (; e + 3 < e1; e += 4) {
            int s0 = col[e], s1 = col[e + 1], s2 = col[e + 2], s3 = col[e + 3];
            h4 h0 = gin[s0 * 8 + q];
            h4 h1 = gin[s1 * 8 + q];
            h4 h2 = gin[s2 * 8 + q];
            h4 h3 = gin[s3 * 8 + q];
            a0 += __builtin_convertvector(h0, f4);
            a1 += __builtin_convertvector(h1, f4);
            a0 += __builtin_convertvector(h2, f4);
            a1 += __builtin_convertvector(h3, f4);
        }
        for (; e < e1; ++e) a0 += __builtin_convertvector(gin[col[e] * 8 + q], f4);
        float di = dinv[n];
        f4 r = di * (a0 + a1);
        hl[nl][q * 4 + 0] = r.x;
        hl[nl][q * 4 + 1] = r.y;
        hl[nl][q * 4 + 2] = r.z;
        hl[nl][q * 4 + 3] = r.w;
    }
    __syncthreads();
    // W row -> registers, conflict-free: lanes o=0..63 read Wl[o][f], bank (o+f)%32
    int o = tid & 63;
    float wreg[F_IN];
#pragma unroll
    for (int f = 0; f < F_IN; ++f) wreg[f] = Wl[o][f];
    float bv = bias[o];
    // 8 passes x 4 nodes: node index wave-uniform -> hl reads broadcast
    int nchunk = tid >> 6;  // 0..3
#pragma unroll
    for (int p = 0; p < 8; ++p) {
        int nloc = p * 4 + nchunk;
        int nn = nbase + nloc;
        if (nn < N) {
            float acc = bv;
#pragma unroll
            for (int f = 0; f < F_IN; ++f) acc += hl[nloc][f] * wreg[f];
            out[(size_t)nn * F_OUT + o] = acc;
        }
    }
}

extern "C" void kernel_launch(void* const* d_in, const int* in_sizes, int n_in,
                              void* d_out, int out_size, void* d_ws, size_t ws_size,
                              hipStream_t stream) {
    const float* x  = (const float*)d_in[0];
    const int*   ei = (const int*)d_in[1];   // [2,E] int32: src row then dst row
    const float* W  = (const float*)d_in[2];
    const float* b  = (const float*)d_in[3];
    float* out = (float*)d_out;

    const int N = in_sizes[0] / F_IN;
    const int E = in_sizes[1] / 2;
    const int NSB  = (N + (1 << SB_SHIFT) - 1) >> SB_SHIFT;   // 13
    const int NSUB = (N + SUB - 1) >> SUB_SHIFT;              // 391

    // ws: scur(16) | subcur(16*32) | rp2(2N) | dinv(N) | b1 | b2 | col | hA hB hB2
    int* scur   = (int*)d_ws;
    int* subcur = scur + NSB_MAX;
    i2*  rp2    = (i2*)(subcur + NSB_MAX * SPS);
    float* dinv = (float*)(rp2 + N);
    unsigned* b1 = (unsigned*)(((uintptr_t)(dinv + N) + 255) & ~(uintptr_t)255);
    unsigned* b2 = b1 + (size_t)NSB_MAX * SCAP;
    int* col     = (int*)(b2 + (size_t)NSB_MAX * SPS * SUBCAP);
    _Float16* hA = (_Float16*)(((uintptr_t)(col + (size_t)NSB_MAX * SPS * SUBCAP) + 255)
                               & ~(uintptr_t)255);
    _Float16* hB  = hA + (size_t)N * F_IN;
    _Float16* hB2 = hB + (size_t)N * F_IN;

    const int B = 256;
    dim3 blk(B);

    hipMemsetAsync(scur, 0, (NSB_MAX + NSB_MAX * SPS) * sizeof(int), stream);

    // two-level radix partition
    k_bin1<<<dim3((E + EPB1 - 1) / EPB1), blk, 0, stream>>>(ei, scur, b1, E);
    k_bin2<<<dim3(NSB * BPS), blk, 0, stream>>>(b1, scur, subcur, b2);

    // per-sub counting sort + fused prescale (g0 -> hA)
    k_fill3<<<dim3(NSUB), blk, 0, stream>>>(b2, subcur, (const f4*)x,
                                            dinv, rp2, col, (h4*)hA, N);

    // hops 1,2: hA -> hB -> hB2
    dim3 gHop(((size_t)N * 8 + B - 1) / B);
    k_hop_gather<<<gHop, blk, 0, stream>>>(rp2, col, dinv, (const h4*)hA, (h4*)hB, N);
    k_hop_gather<<<gHop, blk, 0, stream>>>(rp2, col, dinv, (const h4*)hB, (h4*)hB2, N);

    // hop 3 fused with linear: hB2 -> out
    k_hop3_linear<<<dim3((N + 31) / 32), blk, 0, stream>>>(rp2, col, dinv,
                                                           (const h4*)hB2, W, b, out, N);
}